// Round 3
// baseline (388.624 us; speedup 1.0000x reference)
//
#include <hip/hip_runtime.h>
#include <math.h>

#define N_NODES 50000
#define N_EDGES 800000
#define D_FEAT  128
#define EPSF    1e-12f

// ---------------- workspace layout (bytes) ----------------
#define OFF_U2     0
#define OFF_S      4096
#define OFF_ROWPTR 208896
#define OFF_CURSOR 413696
#define OFF_SSRC   618496
#define OFF_AGG    3818496

// u2[k] = sum_j W_coef[k][j] * W_red[128+j]
__global__ void make_u2_kernel(const float* __restrict__ W_coef,
                               const float* __restrict__ W_red,
                               float* __restrict__ u2) {
    __shared__ float wr[128];
    int k = threadIdx.x;  // 128 threads
    wr[k] = W_red[128 + k];
    __syncthreads();
    const float4* row = (const float4*)(W_coef + k * 128);
    float acc = 0.f;
    #pragma unroll
    for (int j = 0; j < 32; ++j) {
        float4 v = row[j];
        acc += v.x * wr[4*j] + v.y * wr[4*j+1] + v.z * wr[4*j+2] + v.w * wr[4*j+3];
    }
    u2[k] = acc;
}

// s[v] = dot(h[v], u2) ; one wave per node
__global__ __launch_bounds__(256) void node_score_kernel(
        const float* __restrict__ h, const float* __restrict__ u2,
        float* __restrict__ s) {
    int node = blockIdx.x * 4 + (threadIdx.x >> 6);
    int lane = threadIdx.x & 63;
    if (node >= N_NODES) return;
    const float2* hp = (const float2*)(h + (size_t)node * 128);
    const float2* up = (const float2*)u2;
    float2 hv = hp[lane];
    float2 uv = up[lane];
    float v = hv.x * uv.x + hv.y * uv.y;
    #pragma unroll
    for (int off = 32; off; off >>= 1) v += __shfl_down(v, off);
    if (lane == 0) s[node] = v;
}

__global__ void hist_kernel(const int* __restrict__ dst, int* __restrict__ row_ptr) {
    int e = blockIdx.x * blockDim.x + threadIdx.x;
    if (e < N_EDGES) atomicAdd(&row_ptr[dst[e]], 1);
}

// single-block exclusive scan: 1024 threads x 49 elems, shfl wave-scan,
// 2 barriers total (vs 140 in the ladder version).
__global__ __launch_bounds__(1024) void scan_kernel(int* __restrict__ data, int n) {
    const int EPT = 49;  // 1024*49 = 50176 >= 50000
    int tid = threadIdx.x;
    int lane = tid & 63, wid = tid >> 6;
    int base = tid * EPT;
    int vals[EPT];
    int local = 0;
    #pragma unroll
    for (int i = 0; i < EPT; ++i) {
        int id = base + i;
        vals[i] = (id < n) ? data[id] : 0;
        local += vals[i];
    }
    int incl = local;
    #pragma unroll
    for (int off = 1; off < 64; off <<= 1) {
        int t = __shfl_up(incl, off);
        if (lane >= off) incl += t;
    }
    __shared__ int wsum[16];
    if (lane == 63) wsum[wid] = incl;
    __syncthreads();
    if (tid < 16) {
        int v = wsum[tid];
        int s2 = v;
        #pragma unroll
        for (int off = 1; off < 16; off <<= 1) {
            int t = __shfl_up(s2, off);
            if (tid >= off) s2 += t;
        }
        wsum[tid] = s2 - v;  // exclusive wave base
    }
    __syncthreads();
    int excl = wsum[wid] + (incl - local);
    #pragma unroll
    for (int i = 0; i < EPT; ++i) {
        int id = base + i;
        if (id < n) data[id] = excl;
        excl += vals[i];
    }
    if (tid == 1023) data[n] = excl;  // grand total
}

__global__ void scatter_kernel(const int* __restrict__ src, const int* __restrict__ dst,
                               int* __restrict__ cursor, int* __restrict__ ssrc) {
    int e = blockIdx.x * blockDim.x + threadIdx.x;
    if (e < N_EDGES) {
        int p = atomicAdd(&cursor[dst[e]], 1);
        ssrc[p] = src[e];
    }
}

// one wave per node: softmax over incoming edges' s[src], agg = sum alpha * h[src]
__global__ __launch_bounds__(256) void aggregate_kernel(
        const int* __restrict__ row_ptr, const int* __restrict__ ssrc,
        const float* __restrict__ s, const float* __restrict__ h,
        float* __restrict__ agg) {
    int node = blockIdx.x * 4 + (threadIdx.x >> 6);
    int lane = threadIdx.x & 63;
    if (node >= N_NODES) return;
    int beg = row_ptr[node];
    int deg = row_ptr[node + 1] - beg;

    // pass 1: segment max of s[src]
    float m = -INFINITY;
    for (int i = lane; i < deg; i += 64)
        m = fmaxf(m, s[ssrc[beg + i]]);
    #pragma unroll
    for (int off = 32; off; off >>= 1) m = fmaxf(m, __shfl_down(m, off));
    m = __shfl(m, 0);

    // pass 2: weighted accumulate (lane owns features 2*lane, 2*lane+1)
    float2 acc = make_float2(0.f, 0.f);
    float denom = 0.f;
    for (int base = 0; base < deg; base += 64) {
        int cnt = min(64, deg - base);
        int esrc = 0;
        float w_l = 0.f;
        if (lane < cnt) {
            esrc = ssrc[beg + base + lane];
            w_l = __expf(s[esrc] - m);
        }
        for (int j = 0; j < cnt; ++j) {
            int   bsrc = __shfl(esrc, j);
            float w    = __shfl(w_l, j);
            denom += w;
            float2 hv = ((const float2*)(h + (size_t)bsrc * 128))[lane];
            acc.x = fmaf(w, hv.x, acc.x);
            acc.y = fmaf(w, hv.y, acc.y);
        }
    }
    float inv = 1.f / (denom + EPSF);
    ((float2*)(agg + (size_t)node * 128))[lane] = make_float2(acc.x * inv, acc.y * inv);
}

// out[v] = normalize([h[v]@W_node + b_node, agg[v]@W_neigh + b_neigh])
// 64 nodes/block, 128 threads (2 waves). tx=tid&7 owns cols {4tx+32q},
// ty=tid>>3 owns rows {ty+16r : r=0..3}. 4-row register blocking cuts
// LDS bytes/FMA from 2.25 to 1.25. KC=16 chunks; LDS ~34 KB.
#define KC 16
__global__ __launch_bounds__(128, 2) void gemm_norm_kernel(
        const float* __restrict__ h, const float* __restrict__ agg,
        const float* __restrict__ W_node, const float* __restrict__ b_node,
        const float* __restrict__ W_neigh, const float* __restrict__ b_neigh,
        float* __restrict__ out) {
    __shared__ float wn_s[KC * 128];   // 8 KB
    __shared__ float wg_s[KC * 128];   // 8 KB
    __shared__ float h_s[64 * 18];     // 4.5 KB (stride 18: ty*18 mod 32 distinct)
    __shared__ float a_s[64 * 18];     // 4.5 KB
    const int tid = threadIdx.x;
    const int tx = tid & 7;
    const int ty = tid >> 3;           // 0..15
    const int node0 = blockIdx.x * 64;

    float acc1[4][16], acc2[4][16];
    #pragma unroll
    for (int r = 0; r < 4; ++r)
        #pragma unroll
        for (int i = 0; i < 16; ++i) { acc1[r][i] = 0.f; acc2[r][i] = 0.f; }

    for (int kc = 0; kc < 128; kc += KC) {
        __syncthreads();
        // stage weights: KC rows x 128 cols = 512 float4 each
        {
            const float4* wn_g = (const float4*)(W_node + kc * 128);
            const float4* wg_g = (const float4*)(W_neigh + kc * 128);
            float4* wn_d = (float4*)wn_s;
            float4* wg_d = (float4*)wg_s;
            #pragma unroll
            for (int it = 0; it < 4; ++it) {
                int i = tid + it * 128;
                wn_d[i] = wn_g[i];
                wg_d[i] = wg_g[i];
            }
        }
        // stage A: 64 rows x KC cols = 256 float4 each
        #pragma unroll
        for (int it = 0; it < 2; ++it) {
            int i = tid + it * 128;      // 0..255
            int r = i >> 2, c = i & 3;
            int node = node0 + r;
            float4 hv = make_float4(0.f, 0.f, 0.f, 0.f);
            float4 av = make_float4(0.f, 0.f, 0.f, 0.f);
            if (node < N_NODES) {
                hv = *(const float4*)(h   + (size_t)node * 128 + kc + c * 4);
                av = *(const float4*)(agg + (size_t)node * 128 + kc + c * 4);
            }
            float* hd = h_s + r * 18 + c * 4;
            hd[0] = hv.x; hd[1] = hv.y; hd[2] = hv.z; hd[3] = hv.w;
            float* ad = a_s + r * 18 + c * 4;
            ad[0] = av.x; ad[1] = av.y; ad[2] = av.z; ad[3] = av.w;
        }
        __syncthreads();

        #pragma unroll 4
        for (int k = 0; k < KC; ++k) {
            float a1v[4], a2v[4];
            #pragma unroll
            for (int r = 0; r < 4; ++r) {
                a1v[r] = h_s[(ty + 16 * r) * 18 + k];
                a2v[r] = a_s[(ty + 16 * r) * 18 + k];
            }
            const float4* wrn = (const float4*)(wn_s + k * 128);
            const float4* wrg = (const float4*)(wg_s + k * 128);
            #pragma unroll
            for (int q = 0; q < 4; ++q) {
                float4 w1 = wrn[tx + 8 * q];
                float4 w2 = wrg[tx + 8 * q];
                #pragma unroll
                for (int r = 0; r < 4; ++r) {
                    acc1[r][q*4+0] = fmaf(a1v[r], w1.x, acc1[r][q*4+0]);
                    acc1[r][q*4+1] = fmaf(a1v[r], w1.y, acc1[r][q*4+1]);
                    acc1[r][q*4+2] = fmaf(a1v[r], w1.z, acc1[r][q*4+2]);
                    acc1[r][q*4+3] = fmaf(a1v[r], w1.w, acc1[r][q*4+3]);
                    acc2[r][q*4+0] = fmaf(a2v[r], w2.x, acc2[r][q*4+0]);
                    acc2[r][q*4+1] = fmaf(a2v[r], w2.y, acc2[r][q*4+1]);
                    acc2[r][q*4+2] = fmaf(a2v[r], w2.z, acc2[r][q*4+2]);
                    acc2[r][q*4+3] = fmaf(a2v[r], w2.w, acc2[r][q*4+3]);
                }
            }
        }
    }

    // epilogue: bias, sum-sq, cross-tx reduce, normalize, store
    float ss[4] = {0.f, 0.f, 0.f, 0.f};
    #pragma unroll
    for (int q = 0; q < 4; ++q) {
        float4 b1 = *(const float4*)(b_node  + 4 * tx + 32 * q);
        float4 b2 = *(const float4*)(b_neigh + 4 * tx + 32 * q);
        #pragma unroll
        for (int r = 0; r < 4; ++r) {
            acc1[r][q*4+0] += b1.x; acc1[r][q*4+1] += b1.y;
            acc1[r][q*4+2] += b1.z; acc1[r][q*4+3] += b1.w;
            acc2[r][q*4+0] += b2.x; acc2[r][q*4+1] += b2.y;
            acc2[r][q*4+2] += b2.z; acc2[r][q*4+3] += b2.w;
            #pragma unroll
            for (int i = 0; i < 4; ++i) {
                ss[r] = fmaf(acc1[r][q*4+i], acc1[r][q*4+i], ss[r]);
                ss[r] = fmaf(acc2[r][q*4+i], acc2[r][q*4+i], ss[r]);
            }
        }
    }
    #pragma unroll
    for (int r = 0; r < 4; ++r) {
        ss[r] += __shfl_xor(ss[r], 1);
        ss[r] += __shfl_xor(ss[r], 2);
        ss[r] += __shfl_xor(ss[r], 4);
    }
    #pragma unroll
    for (int r = 0; r < 4; ++r) {
        int node = node0 + ty + 16 * r;
        if (node < N_NODES) {
            float scale = rsqrtf(fmaxf(ss[r], EPSF));
            float4* o1 = (float4*)(out + (size_t)node * 256);
            float4* o2 = (float4*)(out + (size_t)node * 256 + 128);
            #pragma unroll
            for (int q = 0; q < 4; ++q) {
                o1[tx + 8 * q] = make_float4(acc1[r][q*4+0] * scale, acc1[r][q*4+1] * scale,
                                             acc1[r][q*4+2] * scale, acc1[r][q*4+3] * scale);
                o2[tx + 8 * q] = make_float4(acc2[r][q*4+0] * scale, acc2[r][q*4+1] * scale,
                                             acc2[r][q*4+2] * scale, acc2[r][q*4+3] * scale);
            }
        }
    }
}

extern "C" void kernel_launch(void* const* d_in, const int* in_sizes, int n_in,
                              void* d_out, int out_size, void* d_ws, size_t ws_size,
                              hipStream_t stream) {
    const float* h       = (const float*)d_in[0];
    const int*   src     = (const int*)d_in[1];
    const int*   dst     = (const int*)d_in[2];
    const float* W_coef  = (const float*)d_in[3];
    // b_coef (d_in[4]) and b_red (d_in[6]) cancel under per-segment softmax shift-invariance
    const float* W_red   = (const float*)d_in[5];
    const float* W_node  = (const float*)d_in[7];
    const float* b_node  = (const float*)d_in[8];
    const float* W_neigh = (const float*)d_in[9];
    const float* b_neigh = (const float*)d_in[10];
    float* out = (float*)d_out;

    char* w = (char*)d_ws;
    float* u2      = (float*)(w + OFF_U2);
    float* s       = (float*)(w + OFF_S);
    int*   row_ptr = (int*)(w + OFF_ROWPTR);
    int*   cursor  = (int*)(w + OFF_CURSOR);
    int*   ssrc    = (int*)(w + OFF_SSRC);
    float* agg     = (float*)(w + OFF_AGG);

    hipMemsetAsync(row_ptr, 0, (N_NODES + 1) * sizeof(int), stream);
    make_u2_kernel<<<1, 128, 0, stream>>>(W_coef, W_red, u2);
    node_score_kernel<<<N_NODES / 4, 256, 0, stream>>>(h, u2, s);
    hist_kernel<<<N_EDGES / 256, 256, 0, stream>>>(dst, row_ptr);
    scan_kernel<<<1, 1024, 0, stream>>>(row_ptr, N_NODES);
    hipMemcpyAsync(cursor, row_ptr, N_NODES * sizeof(int),
                   hipMemcpyDeviceToDevice, stream);
    scatter_kernel<<<N_EDGES / 256, 256, 0, stream>>>(src, dst, cursor, ssrc);
    aggregate_kernel<<<N_NODES / 4, 256, 0, stream>>>(row_ptr, ssrc, s, h, agg);
    gemm_norm_kernel<<<(N_NODES + 63) / 64, 128, 0, stream>>>(
        h, agg, W_node, b_node, W_neigh, b_neigh, out);
}

// Round 4
// 344.997 us; speedup vs baseline: 1.1265x; 1.1265x over previous
//
#include <hip/hip_runtime.h>
#include <hip/hip_bf16.h>
#include <math.h>

#define N_NODES 50000
#define N_EDGES 800000
#define D_FEAT  128
#define EPSF    1e-12f

// ---------------- workspace layout (bytes) ----------------
#define OFF_U2     0
#define OFF_S      4096
#define OFF_ROWPTR 208896
#define OFF_CURSOR 413696          // reused for Wt (bf16) after scatter is done
#define OFF_WTN    413696          // 128*128*2 = 32768 B
#define OFF_WTG    446464          // 32768 B   (cursor region is 200 KB: fits)
#define OFF_SSRC   618496
#define OFF_AGG    3818496

typedef __attribute__((ext_vector_type(8))) short bf8;
typedef __attribute__((ext_vector_type(4))) float f4;

// u2[k] = sum_j W_coef[k][j] * W_red[128+j]
__global__ void make_u2_kernel(const float* __restrict__ W_coef,
                               const float* __restrict__ W_red,
                               float* __restrict__ u2) {
    __shared__ float wr[128];
    int k = threadIdx.x;  // 128 threads
    wr[k] = W_red[128 + k];
    __syncthreads();
    const float4* row = (const float4*)(W_coef + k * 128);
    float acc = 0.f;
    #pragma unroll
    for (int j = 0; j < 32; ++j) {
        float4 v = row[j];
        acc += v.x * wr[4*j] + v.y * wr[4*j+1] + v.z * wr[4*j+2] + v.w * wr[4*j+3];
    }
    u2[k] = acc;
}

// s[v] = dot(h[v], u2) ; one wave per node
__global__ __launch_bounds__(256) void node_score_kernel(
        const float* __restrict__ h, const float* __restrict__ u2,
        float* __restrict__ s) {
    int node = blockIdx.x * 4 + (threadIdx.x >> 6);
    int lane = threadIdx.x & 63;
    if (node >= N_NODES) return;
    const float2* hp = (const float2*)(h + (size_t)node * 128);
    const float2* up = (const float2*)u2;
    float2 hv = hp[lane];
    float2 uv = up[lane];
    float v = hv.x * uv.x + hv.y * uv.y;
    #pragma unroll
    for (int off = 32; off; off >>= 1) v += __shfl_down(v, off);
    if (lane == 0) s[node] = v;
}

__global__ void hist_kernel(const int* __restrict__ dst, int* __restrict__ row_ptr) {
    int e = blockIdx.x * blockDim.x + threadIdx.x;
    if (e < N_EDGES) atomicAdd(&row_ptr[dst[e]], 1);
}

// single-block exclusive scan: 1024 threads x 49 elems, shfl wave-scan
__global__ __launch_bounds__(1024) void scan_kernel(int* __restrict__ data, int n) {
    const int EPT = 49;  // 1024*49 = 50176 >= 50000
    int tid = threadIdx.x;
    int lane = tid & 63, wid = tid >> 6;
    int base = tid * EPT;
    int vals[EPT];
    int local = 0;
    #pragma unroll
    for (int i = 0; i < EPT; ++i) {
        int id = base + i;
        vals[i] = (id < n) ? data[id] : 0;
        local += vals[i];
    }
    int incl = local;
    #pragma unroll
    for (int off = 1; off < 64; off <<= 1) {
        int t = __shfl_up(incl, off);
        if (lane >= off) incl += t;
    }
    __shared__ int wsum[16];
    if (lane == 63) wsum[wid] = incl;
    __syncthreads();
    if (tid < 16) {
        int v = wsum[tid];
        int s2 = v;
        #pragma unroll
        for (int off = 1; off < 16; off <<= 1) {
            int t = __shfl_up(s2, off);
            if (tid >= off) s2 += t;
        }
        wsum[tid] = s2 - v;  // exclusive wave base
    }
    __syncthreads();
    int excl = wsum[wid] + (incl - local);
    #pragma unroll
    for (int i = 0; i < EPT; ++i) {
        int id = base + i;
        if (id < n) data[id] = excl;
        excl += vals[i];
    }
    if (tid == 1023) data[n] = excl;  // grand total
}

__global__ void scatter_kernel(const int* __restrict__ src, const int* __restrict__ dst,
                               int* __restrict__ cursor, int* __restrict__ ssrc) {
    int e = blockIdx.x * blockDim.x + threadIdx.x;
    if (e < N_EDGES) {
        int p = atomicAdd(&cursor[dst[e]], 1);
        ssrc[p] = src[e];
    }
}

// Wt[n][k] = bf16(W[k][n]) for both output weight matrices (128x128 each).
__global__ void prep_weights_kernel(const float* __restrict__ Wn,
                                    const float* __restrict__ Wg,
                                    unsigned short* __restrict__ WtN,
                                    unsigned short* __restrict__ WtG) {
    int idx = blockIdx.x * 256 + threadIdx.x;   // 0..16383
    int n = idx >> 7, k = idx & 127;
    __hip_bfloat16 a = __float2bfloat16(Wn[k * 128 + n]);
    __hip_bfloat16 b = __float2bfloat16(Wg[k * 128 + n]);
    WtN[n * 128 + k] = *(unsigned short*)&a;
    WtG[n * 128 + k] = *(unsigned short*)&b;
}

// one wave per node: softmax over incoming edges' s[src], agg = sum alpha*h[src]
// 2 edges per j-iter: lanes 0-31 handle edge 2j, lanes 32-63 edge 2j+1; each
// half loads a full 512B h-row as float4 (lane owns features 4*l32..+3).
__global__ __launch_bounds__(256) void aggregate_kernel(
        const int* __restrict__ row_ptr, const int* __restrict__ ssrc,
        const float* __restrict__ s, const float* __restrict__ h,
        float* __restrict__ agg) {
    int node = blockIdx.x * 4 + (threadIdx.x >> 6);
    int lane = threadIdx.x & 63;
    if (node >= N_NODES) return;
    int beg = row_ptr[node];
    int deg = row_ptr[node + 1] - beg;
    int half = lane >> 5, l32 = lane & 31;

    // pass 1: segment max of s[src]
    float m = -INFINITY;
    for (int i = lane; i < deg; i += 64)
        m = fmaxf(m, s[ssrc[beg + i]]);
    #pragma unroll
    for (int off = 32; off; off >>= 1) m = fmaxf(m, __shfl_down(m, off));
    m = __shfl(m, 0);

    float4 acc = make_float4(0.f, 0.f, 0.f, 0.f);
    float denom = 0.f;
    for (int base = 0; base < deg; base += 64) {
        int cnt = min(64, deg - base);
        int esrc = 0;
        float w_l = 0.f;
        if (lane < cnt) {
            esrc = ssrc[beg + base + lane];
            w_l = __expf(s[esrc] - m);
        }
        denom += w_l;
        int pairs = (cnt + 1) >> 1;
        for (int j = 0; j < pairs; ++j) {
            int e = 2 * j + half;
            int ec = min(e, cnt - 1);
            int bsrc = __shfl(esrc, ec);
            float w = __shfl(w_l, ec);
            if (e >= cnt) w = 0.f;
            float4 hv = ((const float4*)(h + (size_t)bsrc * 128))[l32];
            acc.x = fmaf(w, hv.x, acc.x);
            acc.y = fmaf(w, hv.y, acc.y);
            acc.z = fmaf(w, hv.z, acc.z);
            acc.w = fmaf(w, hv.w, acc.w);
        }
    }
    // combine the two halves (each lane<->lane^32 hold same features)
    acc.x += __shfl_xor(acc.x, 32);
    acc.y += __shfl_xor(acc.y, 32);
    acc.z += __shfl_xor(acc.z, 32);
    acc.w += __shfl_xor(acc.w, 32);
    #pragma unroll
    for (int off = 32; off; off >>= 1) denom += __shfl_xor(denom, off);
    float inv = 1.f / (denom + EPSF);
    if (half == 0) {
        ((float4*)(agg + (size_t)node * 128))[l32] =
            make_float4(acc.x * inv, acc.y * inv, acc.z * inv, acc.w * inv);
    }
}

__device__ inline bf8 cvt_bf8(float4 a, float4 b) {
    union { bf8 v; __hip_bfloat162 p[4]; } u;
    u.p[0] = __float22bfloat162_rn(make_float2(a.x, a.y));
    u.p[1] = __float22bfloat162_rn(make_float2(a.z, a.w));
    u.p[2] = __float22bfloat162_rn(make_float2(b.x, b.y));
    u.p[3] = __float22bfloat162_rn(make_float2(b.z, b.w));
    return u.v;
}

// out[v] = normalize([h[v]@W_node + b_node, agg[v]@W_neigh + b_neigh])
// MFMA 16x16x32 bf16. 4 waves/block, wave owns 16 complete rows (nodes),
// all 256 output cols -> row-norm reduces within 16-lane quad groups.
// No LDS, no barriers. A frags: 8 consecutive f32 -> cvt_pk_bf16.
// B frags: 16B contiguous from pre-transposed bf16 Wt (L2-hot).
__global__ __launch_bounds__(256) void gemm_norm_mfma(
        const float* __restrict__ h, const float* __restrict__ agg,
        const unsigned short* __restrict__ WtN, const unsigned short* __restrict__ WtG,
        const float* __restrict__ b_node, const float* __restrict__ b_neigh,
        float* __restrict__ out) {
    int wave = threadIdx.x >> 6;
    int lane = threadIdx.x & 63;
    int node0 = blockIdx.x * 64 + wave * 16;
    if (node0 >= N_NODES) return;           // 50000 % 16 == 0: waves all-or-nothing
    int quad = lane >> 4, l16 = lane & 15;
    int arow = node0 + l16;                 // A-operand row for this lane

    f4 accN[8], accG[8];
    #pragma unroll
    for (int t = 0; t < 8; ++t) {
        accN[t] = (f4){0.f, 0.f, 0.f, 0.f};
        accG[t] = (f4){0.f, 0.f, 0.f, 0.f};
    }

    #pragma unroll
    for (int kc = 0; kc < 4; ++kc) {
        int kbase = kc * 32 + quad * 8;     // this lane's 8 k-values
        const float4* ph = (const float4*)(h   + (size_t)arow * 128 + kbase);
        const float4* pa = (const float4*)(agg + (size_t)arow * 128 + kbase);
        bf8 aH = cvt_bf8(ph[0], ph[1]);
        bf8 aG = cvt_bf8(pa[0], pa[1]);
        #pragma unroll
        for (int t = 0; t < 8; ++t) {
            bf8 bN = *(const bf8*)(WtN + (size_t)(t * 16 + l16) * 128 + kbase);
            bf8 bG = *(const bf8*)(WtG + (size_t)(t * 16 + l16) * 128 + kbase);
            accN[t] = __builtin_amdgcn_mfma_f32_16x16x32_bf16(aH, bN, accN[t], 0, 0, 0);
            accG[t] = __builtin_amdgcn_mfma_f32_16x16x32_bf16(aG, bG, accG[t], 0, 0, 0);
        }
    }

    // epilogue: bias, row sum-of-squares (row r lives in this quad's 16 lanes)
    float ssr[4] = {0.f, 0.f, 0.f, 0.f};
    #pragma unroll
    for (int t = 0; t < 8; ++t) {
        float bn = b_node[t * 16 + l16];
        float bg = b_neigh[t * 16 + l16];
        #pragma unroll
        for (int r = 0; r < 4; ++r) {
            accN[t][r] += bn;
            accG[t][r] += bg;
            ssr[r] = fmaf(accN[t][r], accN[t][r], ssr[r]);
            ssr[r] = fmaf(accG[t][r], accG[t][r], ssr[r]);
        }
    }
    #pragma unroll
    for (int r = 0; r < 4; ++r) {
        ssr[r] += __shfl_xor(ssr[r], 1);
        ssr[r] += __shfl_xor(ssr[r], 2);
        ssr[r] += __shfl_xor(ssr[r], 4);
        ssr[r] += __shfl_xor(ssr[r], 8);   // stays within the 16-lane quad group
    }
    #pragma unroll
    for (int r = 0; r < 4; ++r) {
        float sc = rsqrtf(fmaxf(ssr[r], EPSF));
        size_t node = node0 + quad * 4 + r;   // C/D: row = quad*4 + reg
        float* o = out + node * 256;
        #pragma unroll
        for (int t = 0; t < 8; ++t) {
            o[t * 16 + l16]       = accN[t][r] * sc;
            o[128 + t * 16 + l16] = accG[t][r] * sc;
        }
    }
}

extern "C" void kernel_launch(void* const* d_in, const int* in_sizes, int n_in,
                              void* d_out, int out_size, void* d_ws, size_t ws_size,
                              hipStream_t stream) {
    const float* h       = (const float*)d_in[0];
    const int*   src     = (const int*)d_in[1];
    const int*   dst     = (const int*)d_in[2];
    const float* W_coef  = (const float*)d_in[3];
    // b_coef (d_in[4]) and b_red (d_in[6]) cancel under per-segment softmax shift-invariance
    const float* W_red   = (const float*)d_in[5];
    const float* W_node  = (const float*)d_in[7];
    const float* b_node  = (const float*)d_in[8];
    const float* W_neigh = (const float*)d_in[9];
    const float* b_neigh = (const float*)d_in[10];
    float* out = (float*)d_out;

    char* w = (char*)d_ws;
    float* u2      = (float*)(w + OFF_U2);
    float* s       = (float*)(w + OFF_S);
    int*   row_ptr = (int*)(w + OFF_ROWPTR);
    int*   cursor  = (int*)(w + OFF_CURSOR);
    unsigned short* WtN = (unsigned short*)(w + OFF_WTN);
    unsigned short* WtG = (unsigned short*)(w + OFF_WTG);
    int*   ssrc    = (int*)(w + OFF_SSRC);
    float* agg     = (float*)(w + OFF_AGG);

    hipMemsetAsync(row_ptr, 0, (N_NODES + 1) * sizeof(int), stream);
    make_u2_kernel<<<1, 128, 0, stream>>>(W_coef, W_red, u2);
    node_score_kernel<<<N_NODES / 4, 256, 0, stream>>>(h, u2, s);
    hist_kernel<<<N_EDGES / 256, 256, 0, stream>>>(dst, row_ptr);
    scan_kernel<<<1, 1024, 0, stream>>>(row_ptr, N_NODES);
    hipMemcpyAsync(cursor, row_ptr, N_NODES * sizeof(int),
                   hipMemcpyDeviceToDevice, stream);
    scatter_kernel<<<N_EDGES / 256, 256, 0, stream>>>(src, dst, cursor, ssrc);
    // cursor region is dead after scatter: reuse it for the bf16 transposed weights
    prep_weights_kernel<<<64, 256, 0, stream>>>(W_node, W_neigh, WtN, WtG);
    aggregate_kernel<<<N_NODES / 4, 256, 0, stream>>>(row_ptr, ssrc, s, h, agg);
    gemm_norm_mfma<<<(N_NODES + 63) / 64, 256, 0, stream>>>(
        h, agg, WtN, WtG, b_node, b_neigh, out);
}